// Round 11
// baseline (253.305 us; speedup 1.0000x reference)
//
#include <hip/hip_runtime.h>
#include <math.h>

#define NB   2
#define CIN  128
#define CH   64
#define NPOS 4096
#define NBLK 512

typedef __attribute__((ext_vector_type(8))) short s16x8;   // 8 bf16 (4 VGPRs)
typedef __attribute__((ext_vector_type(4))) float f32x4;

// frag-block global layouts (shorts):
//  kF/qF: FB(b, pos-tile16, kc) + lane*8 + elem   (1 KB per frag-block)
//  vF   : VB(b, c-tile16, i-tile32) + lane*8 + elem
#define FB(b,T,kc) ((((size_t)(b) * 256 + (size_t)(T)) * 2 + (size_t)(kc)) * 512)
#define VB(b,ct,it) ((((size_t)(b) * 4 + (size_t)(ct)) * 128 + (size_t)(it)) * 512)

__device__ __forceinline__ unsigned int bfrne(float f) {
    unsigned int u = __float_as_uint(f);
    return (u + 0x7FFFu + ((u >> 16) & 1u)) >> 16;
}
__device__ __forceinline__ unsigned int pk_rne(float lo, float hi) {
    return bfrne(lo) | (bfrne(hi) << 16);
}
// fast half-up pack for non-negative values (exp outputs)
__device__ __forceinline__ unsigned int pk_fast(float lo, float hi) {
    unsigned int a = (__float_as_uint(lo) + 0x8000u) >> 16;
    unsigned int b = (__float_as_uint(hi) + 0x8000u) & 0xFFFF0000u;
    return a | b;
}
__device__ __forceinline__ float bf2f(unsigned short h) {
    return __uint_as_float(((unsigned int)h) << 16);
}

// device-scope (agent) grid barrier; cnt zeroed by init kernel each call.
__device__ __forceinline__ void grid_barrier(int* cnt) {
    __syncthreads();
    if (threadIdx.x == 0) {
        __hip_atomic_fetch_add(cnt, 1, __ATOMIC_ACQ_REL, __HIP_MEMORY_SCOPE_AGENT);
        while (__hip_atomic_load(cnt, __ATOMIC_ACQUIRE, __HIP_MEMORY_SCOPE_AGENT) < NBLK)
            __builtin_amdgcn_s_sleep(2);
    }
    __syncthreads();
}

// ---------------------------------------------------------------------------
// Init: pack all weights to bf16 (Wb = [Wq|Wk|Wv|Wpost], 8192 each) and
// zero the 3 grid-barrier counters.  32 blocks.
// ---------------------------------------------------------------------------
__global__ __launch_bounds__(256) void init_kernel(
    const float* __restrict__ Wq, const float* __restrict__ Wk,
    const float* __restrict__ Wv, const float* __restrict__ Wpost,
    unsigned short* __restrict__ Wb, int* __restrict__ cnt)
{
    const int gid = blockIdx.x * 256 + threadIdx.x;   // 8192 threads
    if (gid < 4) cnt[gid] = 0;
    const int base = gid * 4;
    const int mat = base >> 13, off = base & 8191;
    const float* src = (mat == 0) ? Wq : (mat == 1) ? Wk : (mat == 2) ? Wv : Wpost;
    float4 f = *(const float4*)&src[off];
    uint2 st = make_uint2(pk_rne(f.x, f.y), pk_rne(f.z, f.w));
    *(uint2*)&Wb[mat * 8192 + off] = st;
}

// ---------------------------------------------------------------------------
// Fused kernel: 512 blocks x 256 threads, 4 phases + 3 grid barriers.
//  P1 qkv:  b=g>>8, pt=g&255 (16-pos tile)  -> kF,qF,vF (frag-block layout)
//  P2 stats: b=g>>8, bx=(g&255)>>3, jq=g&7  -> lpart[8][b][i]
//  P3 agg:  b=g>>8, iq=(g&255)>>5, jb=g&31  -> U[8][b][j][c] bf16 partials
//  P4 post: b=g>>8, pt=g&255 (16-pos tile)  -> out = x + Wpost @ sum(U)
// ---------------------------------------------------------------------------
#define XTS 132
__global__ __launch_bounds__(256) void fused_kernel(
    const float* __restrict__ x, const unsigned short* __restrict__ Wb,
    unsigned short* __restrict__ kF, unsigned short* __restrict__ qF,
    unsigned short* __restrict__ vF, float* __restrict__ lpart,
    unsigned short* __restrict__ U, int* __restrict__ cnt,
    float* __restrict__ out)
{
    __shared__ __align__(16) unsigned char smem[8448];
    const int g   = blockIdx.x;
    const int b   = g >> 8;
    const int tid = threadIdx.x;
    const int w = tid >> 6, l = tid & 63, lm = l & 15, lq = l >> 4;

    // ===================== Phase 1: qkv projections =====================
    {
        float* xT = (float*)smem;                  // 16 x 132 fp32
        const int pt = g & 255;
        const int p0 = pt * 16;

        #pragma unroll
        for (int it = 0; it < 2; ++it) {
            int idx = it * 256 + tid;              // 0..511
            int c = idx >> 2, p4 = (idx & 3) * 4;
            float4 gg = *(const float4*)&x[((size_t)b * CIN + c) * NPOS + p0 + p4];
            xT[(p4 + 0) * XTS + c] = gg.x;
            xT[(p4 + 1) * XTS + c] = gg.y;
            xT[(p4 + 2) * XTS + c] = gg.z;
            xT[(p4 + 3) * XTS + c] = gg.w;
        }
        __syncthreads();

        s16x8 Bhi[4], Blo[4];
        #pragma unroll
        for (int ck = 0; ck < 4; ++ck) {
            const float* xr = &xT[lm * XTS + ck * 32 + lq * 8];
            union { unsigned int u[4]; s16x8 v; } chv, clv;
            #pragma unroll
            for (int j = 0; j < 4; ++j) {
                float x0 = xr[2 * j], x1 = xr[2 * j + 1];
                unsigned int h0 = bfrne(x0), h1 = bfrne(x1);
                chv.u[j] = h0 | (h1 << 16);
                clv.u[j] = pk_rne(x0 - __uint_as_float(h0 << 16),
                                  x1 - __uint_as_float(h1 << 16));
            }
            Bhi[ck] = chv.v; Blo[ck] = clv.v;
        }

        #pragma unroll
        for (int t3 = 0; t3 < 3; ++t3) {
            const int tile = w * 3 + t3;
            const int mat = tile >> 2, o0 = (tile & 3) * 16;
            const unsigned short* Wm = Wb + mat * 8192;
            f32x4 acc = {0.f, 0.f, 0.f, 0.f};
            #pragma unroll
            for (int ck = 0; ck < 4; ++ck) {
                s16x8 aW = *(const s16x8*)&Wm[(o0 + lm) * CIN + ck * 32 + lq * 8];
                acc = __builtin_amdgcn_mfma_f32_16x16x32_bf16(aW, Bhi[ck], acc, 0,0,0);
                acc = __builtin_amdgcn_mfma_f32_16x16x32_bf16(aW, Blo[ck], acc, 0,0,0);
            }
            // C-frag: value at (c = o0 + 4*lq + r, p = p0 + lm)
            if (mat < 2) {
                unsigned short* dst = (mat == 0) ? qF : kF;
                const int kc = o0 >> 5;
                const int lane2 = lm + 16 * (((o0 & 31) >> 3) + (lq >> 1));
                uint2 st = make_uint2(pk_rne(acc[0], acc[1]), pk_rne(acc[2], acc[3]));
                *(uint2*)&dst[FB(b, pt, kc) + lane2 * 8 + (lq & 1) * 4] = st;
            } else {
                const int ct = o0 >> 4;
                const int itile = pt >> 1;
                const int lanebase = 16 * ((pt & 1) * 2 + (lm >> 3));
                #pragma unroll
                for (int r = 0; r < 4; ++r)
                    vF[VB(b, ct, itile) + (size_t)(4 * lq + r + lanebase) * 8
                       + (lm & 7)] = (unsigned short)bfrne(acc[r]);
            }
        }
    }

    grid_barrier(&cnt[0]);

    // ===================== Phase 2: softmax denominators =====================
    {
        const int r2 = g & 255;
        const int jq = r2 & 7;
        const int it = (r2 >> 3) * 4 + w;          // 32-i tile, 0..127

        s16x8 a[2][2];
        #pragma unroll
        for (int s = 0; s < 2; ++s)
            #pragma unroll
            for (int kc = 0; kc < 2; ++kc)
                a[s][kc] = *(const s16x8*)&kF[FB(b, it * 2 + s, kc) + l * 8];

        const unsigned short* q0 = qF + FB(b, jq * 32, 0);
        s16x8 nb0 = *(const s16x8*)&q0[l * 8];
        s16x8 nb1 = *(const s16x8*)&q0[512 + l * 8];

        float rs[2][4] = {};
        for (int t = 0; t < 32; ++t) {
            s16x8 b0 = nb0, b1 = nb1;
            if (t < 31) {
                nb0 = *(const s16x8*)&q0[(size_t)(t + 1) * 1024 + l * 8];
                nb1 = *(const s16x8*)&q0[(size_t)(t + 1) * 1024 + 512 + l * 8];
            }
            #pragma unroll
            for (int s = 0; s < 2; ++s) {
                f32x4 sc = {0.f, 0.f, 0.f, 0.f};
                sc = __builtin_amdgcn_mfma_f32_16x16x32_bf16(a[s][0], b0, sc, 0,0,0);
                sc = __builtin_amdgcn_mfma_f32_16x16x32_bf16(a[s][1], b1, sc, 0,0,0);
                rs[s][0] += __expf(sc[0]); rs[s][1] += __expf(sc[1]);
                rs[s][2] += __expf(sc[2]); rs[s][3] += __expf(sc[3]);
            }
        }

        #pragma unroll
        for (int s = 0; s < 2; ++s)
            #pragma unroll
            for (int r = 0; r < 4; ++r) {
                rs[s][r] += __shfl_xor(rs[s][r], 1);
                rs[s][r] += __shfl_xor(rs[s][r], 2);
                rs[s][r] += __shfl_xor(rs[s][r], 4);
                rs[s][r] += __shfl_xor(rs[s][r], 8);
            }
        if (lm == 0) {
            #pragma unroll
            for (int s = 0; s < 2; ++s)
                #pragma unroll
                for (int r = 0; r < 4; ++r)
                    lpart[(size_t)jq * NB * NPOS + b * NPOS
                          + it * 32 + s * 16 + lq * 4 + r] = rs[s][r];
        }
    }

    grid_barrier(&cnt[1]);

    // ===================== Phase 3: aggregation =====================
    {
        unsigned short* wts = (unsigned short*)smem;       // [4][16][40]
        float* rls = (float*)(smem + 5120);                // [512]
        const int r3 = g & 255;
        const int iq = r3 >> 5;
        const int jb = r3 & 31;
        const int j0 = jb * 128;

        {
            const float* lp = lpart + (size_t)b * NPOS + iq * 512 + tid * 2;
            float s0 = 0.f, s1 = 0.f;
            #pragma unroll
            for (int qq = 0; qq < 8; ++qq) {
                float2 lv = *(const float2*)(lp + (size_t)qq * NB * NPOS);
                s0 += lv.x; s1 += lv.y;
            }
            rls[tid * 2 + 0] = 1.0f / s0;
            rls[tid * 2 + 1] = 1.0f / s1;
        }

        s16x8 qb[2][2];
        #pragma unroll
        for (int js = 0; js < 2; ++js)
            #pragma unroll
            for (int kc = 0; kc < 2; ++kc)
                qb[js][kc] = *(const s16x8*)&qF[
                    FB(b, jb * 8 + w * 2 + js, kc) + l * 8];

        f32x4 acc[2][4] = {};
        s16x8 nk[2][2], nv[4];
        #pragma unroll
        for (int s = 0; s < 2; ++s)
            #pragma unroll
            for (int kc = 0; kc < 2; ++kc)
                nk[s][kc] = *(const s16x8*)&kF[FB(b, iq * 32 + s, kc) + l * 8];
        #pragma unroll
        for (int cs = 0; cs < 4; ++cs)
            nv[cs] = *(const s16x8*)&vF[VB(b, cs, iq * 16) + l * 8];

        __syncthreads();   // rls ready

        for (int t = 0; t < 16; ++t) {
            s16x8 kA[2][2] = {{nk[0][0], nk[0][1]}, {nk[1][0], nk[1][1]}};
            s16x8 vA[4] = {nv[0], nv[1], nv[2], nv[3]};
            if (t < 15) {
                #pragma unroll
                for (int s = 0; s < 2; ++s)
                    #pragma unroll
                    for (int kc = 0; kc < 2; ++kc)
                        nk[s][kc] = *(const s16x8*)&kF[
                            FB(b, iq * 32 + (t + 1) * 2 + s, kc) + l * 8];
                #pragma unroll
                for (int cs = 0; cs < 4; ++cs)
                    nv[cs] = *(const s16x8*)&vF[VB(b, cs, iq * 16 + t + 1) + l * 8];
            }

            f32x4 rl0 = *(const f32x4*)&rls[t * 32 + lq * 4];
            f32x4 rl1 = *(const f32x4*)&rls[t * 32 + 16 + lq * 4];

            #pragma unroll
            for (int js = 0; js < 2; ++js) {
                f32x4 s0 = {0,0,0,0}, s1 = {0,0,0,0};
                s0 = __builtin_amdgcn_mfma_f32_16x16x32_bf16(kA[0][0], qb[js][0], s0, 0,0,0);
                s0 = __builtin_amdgcn_mfma_f32_16x16x32_bf16(kA[0][1], qb[js][1], s0, 0,0,0);
                s1 = __builtin_amdgcn_mfma_f32_16x16x32_bf16(kA[1][0], qb[js][0], s1, 0,0,0);
                s1 = __builtin_amdgcn_mfma_f32_16x16x32_bf16(kA[1][1], qb[js][1], s1, 0,0,0);

                unsigned int P0[2], P1[2];
                P0[0] = pk_fast(__expf(s0[0]) * rl0[0], __expf(s0[1]) * rl0[1]);
                P0[1] = pk_fast(__expf(s0[2]) * rl0[2], __expf(s0[3]) * rl0[3]);
                P1[0] = pk_fast(__expf(s1[0]) * rl1[0], __expf(s1[1]) * rl1[1]);
                P1[1] = pk_fast(__expf(s1[2]) * rl1[2], __expf(s1[3]) * rl1[3]);

                // wave-private C->B transpose via LDS roundtrip (no barrier)
                unsigned short* wr = wts + w * 640 + lm * 40;
                *(uint2*)&wr[4 * lq]      = make_uint2(P0[0], P0[1]);
                *(uint2*)&wr[16 + 4 * lq] = make_uint2(P1[0], P1[1]);
                s16x8 Bv = *(const s16x8*)&wr[8 * lq];

                #pragma unroll
                for (int cs = 0; cs < 4; ++cs)
                    acc[js][cs] = __builtin_amdgcn_mfma_f32_16x16x32_bf16(
                        vA[cs], Bv, acc[js][cs], 0,0,0);
            }
        }

        unsigned short* Up = U + ((size_t)iq * NB + b) * NPOS * CH;
        #pragma unroll
        for (int js = 0; js < 2; ++js)
            #pragma unroll
            for (int cs = 0; cs < 4; ++cs) {
                uint2 st = make_uint2(pk_rne(acc[js][cs][0], acc[js][cs][1]),
                                      pk_rne(acc[js][cs][2], acc[js][cs][3]));
                *(uint2*)&Up[(size_t)(j0 + w * 32 + js * 16 + lm) * CH
                             + cs * 16 + lq * 4] = st;
            }
    }

    grid_barrier(&cnt[2]);

    // ===================== Phase 4: post projection + residual =====================
    {
        const int pt = g & 255;
        const int p = pt * 16 + lm;
        const size_t PS = (size_t)NB * NPOS * CH;

        const unsigned short* u = U + ((size_t)b * NPOS + p) * CH;
        const unsigned short* Wpb = Wb + 3 * 8192;
        s16x8 Bf[2];
        #pragma unroll
        for (int ck = 0; ck < 2; ++ck) {
            float sv[8] = {};
            #pragma unroll
            for (int qq = 0; qq < 8; ++qq) {
                union { s16x8 v; unsigned short us[8]; } uu;
                uu.v = *(const s16x8*)(u + (size_t)qq * PS + ck * 32 + lq * 8);
                #pragma unroll
                for (int j = 0; j < 8; ++j) sv[j] += bf2f(uu.us[j]);
            }
            union { unsigned int u[4]; s16x8 v; } cb;
            #pragma unroll
            for (int j = 0; j < 4; ++j) cb.u[j] = pk_rne(sv[2*j], sv[2*j+1]);
            Bf[ck] = cb.v;
        }

        #pragma unroll
        for (int ot = 0; ot < 2; ++ot) {
            const int o0 = (w * 2 + ot) * 16;
            f32x4 acc = {0.f, 0.f, 0.f, 0.f};
            #pragma unroll
            for (int ck = 0; ck < 2; ++ck) {
                s16x8 aW = *(const s16x8*)&Wpb[(o0 + lm) * CH + ck * 32 + lq * 8];
                acc = __builtin_amdgcn_mfma_f32_16x16x32_bf16(aW, Bf[ck], acc, 0,0,0);
            }
            #pragma unroll
            for (int r = 0; r < 4; ++r) {
                size_t gi = ((size_t)b * CIN + o0 + lq * 4 + r) * NPOS + p;
                out[gi] = x[gi] + acc[r];
            }
        }
    }
}

extern "C" void kernel_launch(void* const* d_in, const int* in_sizes, int n_in,
                              void* d_out, int out_size, void* d_ws, size_t ws_size,
                              hipStream_t stream) {
    const float* x     = (const float*)d_in[0];
    const float* Wq    = (const float*)d_in[1];
    const float* Wk    = (const float*)d_in[2];
    const float* Wv    = (const float*)d_in[3];
    const float* Wpost = (const float*)d_in[4];
    float* out = (float*)d_out;

    // ws: Wb(64KB) kF(1MB) qF(1MB) vF(1MB) lpart(256KB) U(8MB) cnt(16B)
    unsigned short* Wb = (unsigned short*)d_ws;
    unsigned short* kF = Wb + 4 * 8192;
    unsigned short* qF = kF + (size_t)NB * NPOS * CH;
    unsigned short* vF = qF + (size_t)NB * NPOS * CH;
    float* lpart = (float*)(vF + (size_t)NB * NPOS * CH);
    unsigned short* U = (unsigned short*)(lpart + (size_t)8 * NB * NPOS);
    int* cnt = (int*)(U + (size_t)8 * NB * NPOS * CH);

    init_kernel <<<dim3(32),   256, 0, stream>>>(Wq, Wk, Wv, Wpost, Wb, cnt);
    fused_kernel<<<dim3(NBLK), 256, 0, stream>>>(x, Wb, kF, qF, vF, lpart, U,
                                                 cnt, out);
}

// Round 12
// 113.254 us; speedup vs baseline: 2.2366x; 2.2366x over previous
//
#include <hip/hip_runtime.h>
#include <math.h>

#define NB   2
#define CIN  128
#define CH   64
#define NPOS 4096

typedef __attribute__((ext_vector_type(8))) short s16x8;   // 8 bf16 (4 VGPRs)
typedef __attribute__((ext_vector_type(4))) float f32x4;

// frag-block global layouts (shorts):
//  kF/qF: FB(b, pos-tile16, kc) + lane*8 + elem   (1 KB per frag-block)
//  vF   : VB(b, c-tile16, i-tile32) + lane*8 + elem
#define FB(b,T,kc) ((((size_t)(b) * 256 + (size_t)(T)) * 2 + (size_t)(kc)) * 512)
#define VB(b,ct,it) ((((size_t)(b) * 4 + (size_t)(ct)) * 128 + (size_t)(it)) * 512)

__device__ __forceinline__ unsigned int bfrne(float f) {
    unsigned int u = __float_as_uint(f);
    return (u + 0x7FFFu + ((u >> 16) & 1u)) >> 16;
}
__device__ __forceinline__ unsigned int pk_rne(float lo, float hi) {
    return bfrne(lo) | (bfrne(hi) << 16);
}
// fast half-up pack for non-negative values (exp outputs)
__device__ __forceinline__ unsigned int pk_fast(float lo, float hi) {
    unsigned int a = (__float_as_uint(lo) + 0x8000u) >> 16;
    unsigned int b = (__float_as_uint(hi) + 0x8000u) & 0xFFFF0000u;
    return a | b;
}
__device__ __forceinline__ float bf2f(unsigned short h) {
    return __uint_as_float(((unsigned int)h) << 16);
}

// ---------------------------------------------------------------------------
// Kernel 1: q/k/v projections via MFMA -> frag-block layouts.
// Grid (256 pt, 3 og, b) = 1536 blocks (~6/CU).  Each wave does ONE 16-o
// tile (tile = og*4 + w).  x staged+transposed in LDS; B = x split hi+lo
// bf16; A = W packed bf16 in-register from fp32 (L2-hot).
// ---------------------------------------------------------------------------
#define XTS 132
__global__ __launch_bounds__(256, 4) void qkv_kernel(
    const float* __restrict__ x,
    const float* __restrict__ Wq, const float* __restrict__ Wk,
    const float* __restrict__ Wv,
    unsigned short* __restrict__ kF, unsigned short* __restrict__ qF,
    unsigned short* __restrict__ vF)
{
    __shared__ __align__(16) float xT[16 * XTS];   // 8.25 KB
    const int b  = blockIdx.z;
    const int og = blockIdx.y;
    const int pt = blockIdx.x;                     // 16-pos tile index
    const int p0 = pt * 16;
    const int tid = threadIdx.x;

    #pragma unroll
    for (int it = 0; it < 2; ++it) {
        int idx = it * 256 + tid;                  // 0..511
        int c = idx >> 2, p4 = (idx & 3) * 4;
        float4 g = *(const float4*)&x[((size_t)b * CIN + c) * NPOS + p0 + p4];
        xT[(p4 + 0) * XTS + c] = g.x;
        xT[(p4 + 1) * XTS + c] = g.y;
        xT[(p4 + 2) * XTS + c] = g.z;
        xT[(p4 + 3) * XTS + c] = g.w;
    }
    __syncthreads();

    const int w = tid >> 6, l = tid & 63, lm = l & 15, lq = l >> 4;

    s16x8 Bhi[4], Blo[4];
    #pragma unroll
    for (int ck = 0; ck < 4; ++ck) {
        const float* xr = &xT[lm * XTS + ck * 32 + lq * 8];
        union { unsigned int u[4]; s16x8 v; } chv, clv;
        #pragma unroll
        for (int j = 0; j < 4; ++j) {
            float x0 = xr[2 * j], x1 = xr[2 * j + 1];
            unsigned int h0 = bfrne(x0), h1 = bfrne(x1);
            chv.u[j] = h0 | (h1 << 16);
            clv.u[j] = pk_rne(x0 - __uint_as_float(h0 << 16),
                              x1 - __uint_as_float(h1 << 16));
        }
        Bhi[ck] = chv.v; Blo[ck] = clv.v;
    }

    const int tile = og * 4 + w;                   // 0..11
    const int mat = tile >> 2, o0 = (tile & 3) * 16;
    const float* __restrict__ W = (mat == 0) ? Wq : (mat == 1) ? Wk : Wv;
    f32x4 acc = {0.f, 0.f, 0.f, 0.f};
    #pragma unroll
    for (int ck = 0; ck < 4; ++ck) {
        const float* wp = W + (o0 + lm) * CIN + ck * 32 + lq * 8;
        union { unsigned int u[4]; s16x8 v; } ca;
        #pragma unroll
        for (int j = 0; j < 4; ++j) ca.u[j] = pk_rne(wp[2*j], wp[2*j+1]);
        acc = __builtin_amdgcn_mfma_f32_16x16x32_bf16(ca.v, Bhi[ck], acc, 0,0,0);
        acc = __builtin_amdgcn_mfma_f32_16x16x32_bf16(ca.v, Blo[ck], acc, 0,0,0);
    }
    // C-frag: value at (c = o0 + 4*lq + r, p = p0 + lm)
    if (mat < 2) {
        unsigned short* dst = (mat == 0) ? qF : kF;
        const int kc = o0 >> 5;
        const int lane2 = lm + 16 * (((o0 & 31) >> 3) + (lq >> 1));
        uint2 st = make_uint2(pk_rne(acc[0], acc[1]), pk_rne(acc[2], acc[3]));
        *(uint2*)&dst[FB(b, pt, kc) + lane2 * 8 + (lq & 1) * 4] = st;
    } else {
        const int ct = o0 >> 4;
        const int itile = pt >> 1;
        const int lanebase = 16 * ((pt & 1) * 2 + (lm >> 3));
        #pragma unroll
        for (int r = 0; r < 4; ++r)
            vF[VB(b, ct, itile) + (size_t)(4 * lq + r + lanebase) * 8
               + (lm & 7)] = (unsigned short)bfrne(acc[r]);
    }
}

// ---------------------------------------------------------------------------
// Kernel 2: softmax denominator partials over j-SIXTEENTHS.  Grid (32, 16,
// b) = 1024 blocks (4/CU).  Each WAVE owns one 32-i tile (it = bx*4+w,
// 0..127) and sweeps its 256-j slice: NO LDS, NO barriers; coalesced b128
// fragment loads, prefetched 1 ahead.
// ---------------------------------------------------------------------------
__global__ __launch_bounds__(256, 4) void stats_kernel(
    const unsigned short* __restrict__ kF,
    const unsigned short* __restrict__ qF,
    float* __restrict__ lpart)
{
    const int b  = blockIdx.z;
    const int jq = blockIdx.y;                     // 0..15
    const int tid = threadIdx.x;
    const int w = tid >> 6, l = tid & 63, lm = l & 15, lq = l >> 4;
    const int it = blockIdx.x * 4 + w;             // 32-i tile, 0..127

    s16x8 a[2][2];
    #pragma unroll
    for (int s = 0; s < 2; ++s)
        #pragma unroll
        for (int kc = 0; kc < 2; ++kc)
            a[s][kc] = *(const s16x8*)&kF[FB(b, it * 2 + s, kc) + l * 8];

    const unsigned short* q0 = qF + FB(b, jq * 16, 0);   // 16 j-tiles
    s16x8 nb0 = *(const s16x8*)&q0[l * 8];
    s16x8 nb1 = *(const s16x8*)&q0[512 + l * 8];

    float rs[2][4] = {};
    for (int t = 0; t < 16; ++t) {
        s16x8 b0 = nb0, b1 = nb1;
        if (t < 15) {
            nb0 = *(const s16x8*)&q0[(size_t)(t + 1) * 1024 + l * 8];
            nb1 = *(const s16x8*)&q0[(size_t)(t + 1) * 1024 + 512 + l * 8];
        }
        #pragma unroll
        for (int s = 0; s < 2; ++s) {
            f32x4 sc = {0.f, 0.f, 0.f, 0.f};
            sc = __builtin_amdgcn_mfma_f32_16x16x32_bf16(a[s][0], b0, sc, 0,0,0);
            sc = __builtin_amdgcn_mfma_f32_16x16x32_bf16(a[s][1], b1, sc, 0,0,0);
            rs[s][0] += __expf(sc[0]); rs[s][1] += __expf(sc[1]);
            rs[s][2] += __expf(sc[2]); rs[s][3] += __expf(sc[3]);
        }
    }

    #pragma unroll
    for (int s = 0; s < 2; ++s)
        #pragma unroll
        for (int r = 0; r < 4; ++r) {
            rs[s][r] += __shfl_xor(rs[s][r], 1);
            rs[s][r] += __shfl_xor(rs[s][r], 2);
            rs[s][r] += __shfl_xor(rs[s][r], 4);
            rs[s][r] += __shfl_xor(rs[s][r], 8);
        }
    if (lm == 0) {
        #pragma unroll
        for (int s = 0; s < 2; ++s)
            #pragma unroll
            for (int r = 0; r < 4; ++r)
                lpart[(size_t)jq * NB * NPOS + b * NPOS
                      + it * 32 + s * 16 + lq * 4 + r] = rs[s][r];
    }
}

// ---------------------------------------------------------------------------
// Kernel 3: aggregation, j-split.  Grid (64 jb, 8 iq, b) = 1024 blocks
// (4/CU).  U[iq][b][j][c] bf16 partials (8 partials, unchanged traffic).
// Wave owns 16 j (1 q-frag set, 64c x 16j acc); per 32-i iter: k (4 b128)
// + v (4 b128) direct frag-block loads (prefetched 1 ahead; 4x intra-block
// redundancy L1-served); 4 score MFMAs -> exp*rl -> wave-private LDS
// roundtrip transpose -> 4 PV MFMAs.  gl reduced inline (16 partials).
// ---------------------------------------------------------------------------
__global__ __launch_bounds__(256, 4) void agg_kernel(
    const unsigned short* __restrict__ kF,
    const unsigned short* __restrict__ qF,
    const unsigned short* __restrict__ vF,
    const float* __restrict__ lpart,
    unsigned short* __restrict__ U)
{
    __shared__ __align__(16) unsigned short wts[4][16][40];  // 5 KB
    __shared__ __align__(16) float rls[512];                 // 2 KB
    const int b  = blockIdx.z;
    const int iq = blockIdx.y;
    const int jb = blockIdx.x;
    const int j0 = jb * 64;
    const int tid = threadIdx.x;
    const int w = tid >> 6, l = tid & 63, lm = l & 15, lq = l >> 4;

    // inline gl: reduce 16 lpart partials for this block's 512-i slice
    {
        const float* lp = lpart + (size_t)b * NPOS + iq * 512 + tid * 2;
        float s0 = 0.f, s1 = 0.f;
        #pragma unroll
        for (int qq = 0; qq < 16; ++qq) {
            float2 lv = *(const float2*)(lp + (size_t)qq * NB * NPOS);
            s0 += lv.x; s1 += lv.y;
        }
        rls[tid * 2 + 0] = 1.0f / s0;
        rls[tid * 2 + 1] = 1.0f / s1;
    }

    s16x8 qb[2];
    #pragma unroll
    for (int kc = 0; kc < 2; ++kc)
        qb[kc] = *(const s16x8*)&qF[FB(b, jb * 4 + w, kc) + l * 8];

    f32x4 acc[4] = {};
    s16x8 nk[2][2], nv[4];
    #pragma unroll
    for (int s = 0; s < 2; ++s)
        #pragma unroll
        for (int kc = 0; kc < 2; ++kc)
            nk[s][kc] = *(const s16x8*)&kF[FB(b, iq * 32 + s, kc) + l * 8];
    #pragma unroll
    for (int cs = 0; cs < 4; ++cs)
        nv[cs] = *(const s16x8*)&vF[VB(b, cs, iq * 16) + l * 8];

    __syncthreads();   // rls ready (only barrier)

    for (int t = 0; t < 16; ++t) {
        s16x8 k00 = nk[0][0], k01 = nk[0][1], k10 = nk[1][0], k11 = nk[1][1];
        s16x8 v0 = nv[0], v1 = nv[1], v2 = nv[2], v3 = nv[3];
        if (t < 15) {
            #pragma unroll
            for (int s = 0; s < 2; ++s)
                #pragma unroll
                for (int kc = 0; kc < 2; ++kc)
                    nk[s][kc] = *(const s16x8*)&kF[
                        FB(b, iq * 32 + (t + 1) * 2 + s, kc) + l * 8];
            #pragma unroll
            for (int cs = 0; cs < 4; ++cs)
                nv[cs] = *(const s16x8*)&vF[VB(b, cs, iq * 16 + t + 1) + l * 8];
        }

        f32x4 rl0 = *(const f32x4*)&rls[t * 32 + lq * 4];
        f32x4 rl1 = *(const f32x4*)&rls[t * 32 + 16 + lq * 4];

        f32x4 s0 = {0,0,0,0}, s1 = {0,0,0,0};
        s0 = __builtin_amdgcn_mfma_f32_16x16x32_bf16(k00, qb[0], s0, 0,0,0);
        s0 = __builtin_amdgcn_mfma_f32_16x16x32_bf16(k01, qb[1], s0, 0,0,0);
        s1 = __builtin_amdgcn_mfma_f32_16x16x32_bf16(k10, qb[0], s1, 0,0,0);
        s1 = __builtin_amdgcn_mfma_f32_16x16x32_bf16(k11, qb[1], s1, 0,0,0);

        unsigned int P0[2], P1[2];
        P0[0] = pk_fast(__expf(s0[0]) * rl0[0], __expf(s0[1]) * rl0[1]);
        P0[1] = pk_fast(__expf(s0[2]) * rl0[2], __expf(s0[3]) * rl0[3]);
        P1[0] = pk_fast(__expf(s1[0]) * rl1[0], __expf(s1[1]) * rl1[1]);
        P1[1] = pk_fast(__expf(s1[2]) * rl1[2], __expf(s1[3]) * rl1[3]);

        // wave-private C->B transpose via LDS roundtrip (no barrier)
        unsigned short* wr = &wts[w][lm][0];
        *(uint2*)&wr[4 * lq]      = make_uint2(P0[0], P0[1]);
        *(uint2*)&wr[16 + 4 * lq] = make_uint2(P1[0], P1[1]);
        s16x8 Bv = *(const s16x8*)&wr[8 * lq];

        #pragma unroll
        for (int cs = 0; cs < 4; ++cs)
            acc[cs] = __builtin_amdgcn_mfma_f32_16x16x32_bf16(
                v0, Bv, acc[cs], 0,0,0), v0 = (cs == 0) ? v1 : (cs == 1) ? v2 : v3;
    }

    unsigned short* Up = U + ((size_t)iq * NB + b) * NPOS * CH;
    #pragma unroll
    for (int cs = 0; cs < 4; ++cs) {
        uint2 st = make_uint2(pk_rne(acc[cs][0], acc[cs][1]),
                              pk_rne(acc[cs][2], acc[cs][3]));
        *(uint2*)&Up[(size_t)(j0 + w * 16 + lm) * CH + cs * 16 + lq * 4] = st;
    }
}

// ---------------------------------------------------------------------------
// Kernel 4: post projection + residual.  Grid (256 pt, 2 og, b) = 1024
// blocks (4/CU).  Wave does ONE 16-o tile (og*4 + w).  B = sum of 8 bf16 U
// partials (fp32 accumulate), A = Wpost packed bf16 in-register, + x.
// ---------------------------------------------------------------------------
__global__ __launch_bounds__(256, 4) void post_kernel(
    const float* __restrict__ x, const float* __restrict__ Wpost,
    const unsigned short* __restrict__ U, float* __restrict__ out)
{
    const int b  = blockIdx.z;
    const int og = blockIdx.y;
    const int p0 = blockIdx.x * 16;
    const int tid = threadIdx.x;
    const int w = tid >> 6, l = tid & 63, lm = l & 15, lq = l >> 4;
    const int p = p0 + lm;
    const size_t PS = (size_t)NB * NPOS * CH;

    const unsigned short* u = U + ((size_t)b * NPOS + p) * CH;
    s16x8 Bf[2];
    #pragma unroll
    for (int ck = 0; ck < 2; ++ck) {
        float sv[8] = {};
        #pragma unroll
        for (int qq = 0; qq < 8; ++qq) {
            union { s16x8 v; unsigned short us[8]; } uu;
            uu.v = *(const s16x8*)(u + (size_t)qq * PS + ck * 32 + lq * 8);
            #pragma unroll
            for (int j = 0; j < 8; ++j) sv[j] += bf2f(uu.us[j]);
        }
        union { unsigned int u[4]; s16x8 v; } cb;
        #pragma unroll
        for (int j = 0; j < 4; ++j) cb.u[j] = pk_rne(sv[2*j], sv[2*j+1]);
        Bf[ck] = cb.v;
    }

    const int o0 = (og * 4 + w) * 16;
    f32x4 acc = {0.f, 0.f, 0.f, 0.f};
    #pragma unroll
    for (int ck = 0; ck < 2; ++ck) {
        const float* wp = Wpost + (o0 + lm) * CH + ck * 32 + lq * 8;
        union { unsigned int u[4]; s16x8 v; } ca;
        #pragma unroll
        for (int j = 0; j < 4; ++j) ca.u[j] = pk_rne(wp[2*j], wp[2*j+1]);
        acc = __builtin_amdgcn_mfma_f32_16x16x32_bf16(ca.v, Bf[ck], acc, 0,0,0);
    }
    #pragma unroll
    for (int r = 0; r < 4; ++r) {
        size_t gi = ((size_t)b * CIN + o0 + lq * 4 + r) * NPOS + p;
        out[gi] = x[gi] + acc[r];
    }
}

extern "C" void kernel_launch(void* const* d_in, const int* in_sizes, int n_in,
                              void* d_out, int out_size, void* d_ws, size_t ws_size,
                              hipStream_t stream) {
    const float* x     = (const float*)d_in[0];
    const float* Wq    = (const float*)d_in[1];
    const float* Wk    = (const float*)d_in[2];
    const float* Wv    = (const float*)d_in[3];
    const float* Wpost = (const float*)d_in[4];
    float* out = (float*)d_out;

    // ws: kF(1MB) qF(1MB) vF(1MB) lpart(512KB, 16 partials) U(8MB bf16)
    unsigned short* kF = (unsigned short*)d_ws;
    unsigned short* qF = kF + (size_t)NB * NPOS * CH;
    unsigned short* vF = qF + (size_t)NB * NPOS * CH;
    float* lpart = (float*)(vF + (size_t)NB * NPOS * CH);
    unsigned short* U = (unsigned short*)(lpart + (size_t)16 * NB * NPOS);

    qkv_kernel  <<<dim3(NPOS / 16, 3, NB), 256, 0, stream>>>(x, Wq, Wk, Wv, kF, qF, vF);
    stats_kernel<<<dim3(32, 16, NB),       256, 0, stream>>>(kF, qF, lpart);
    agg_kernel  <<<dim3(64, 8, NB),        256, 0, stream>>>(kF, qF, vF, lpart, U);
    post_kernel <<<dim3(NPOS / 16, 2, NB), 256, 0, stream>>>(x, Wpost, U, out);
}